// Round 4
// baseline (1966.030 us; speedup 1.0000x reference)
//
#include <hip/hip_runtime.h>
#include <hip/hip_bf16.h>
#include <cstddef>

#define DD   128
#define PP   8192
#define KK   8
#define NN   131072
#define NE   65536
#define NLVL 15
#define AST  136   // A-stage row stride in bf16 (+8 pad -> 272B)
#define NBLK 256

typedef __bf16 bf16x8 __attribute__((ext_vector_type(8)));
typedef float  f32x4  __attribute__((ext_vector_type(4)));

__device__ __forceinline__ float bf_lo(unsigned u) { return __uint_as_float(u << 16); }
__device__ __forceinline__ float bf_hi(unsigned u) { return __uint_as_float(u & 0xffff0000u); }

struct GiphParams {
  const float* x; const int* src;
  const float* nt_w1; const float* nt_b1; const float* nt_w2; const float* nt_b2;
  const float* f_pre_w; const float* f_pre_b; const float* f_upd_w; const float* f_upd_b;
  const float* b_pre_w; const float* b_pre_b; const float* b_upd_w; const float* b_upd_b;
  float* out; float* h;
  __bf16* mf0; __bf16* mf1; __bf16* mb0; __bf16* mb1;
  __bf16* wpk; int* deg; int* offs; int* cursor; int* edges;
  int* bar;   // [0]=arrive count, [16]=generation (separate cachelines-ish)
};

// Software grid barrier. Safe because LDS (81 KB) forces 1 block/CU and
// grid == 256 == CU count -> all blocks co-resident by construction.
__device__ __forceinline__ void grid_barrier(int* bar, int tid) {
  __syncthreads();                       // all block stores issued (waitcnt before s_barrier)
  if (tid == 0) {
    __threadfence();                     // agent-scope release: XCD L2 writeback
    int gen = __hip_atomic_load(bar + 16, __ATOMIC_RELAXED, __HIP_MEMORY_SCOPE_AGENT);
    int a = __hip_atomic_fetch_add(bar, 1, __ATOMIC_ACQ_REL, __HIP_MEMORY_SCOPE_AGENT);
    if (a == NBLK - 1) {
      __hip_atomic_store(bar, 0, __ATOMIC_RELAXED, __HIP_MEMORY_SCOPE_AGENT);
      __hip_atomic_fetch_add(bar + 16, 1, __ATOMIC_RELEASE, __HIP_MEMORY_SCOPE_AGENT);
    } else {
      while (__hip_atomic_load(bar + 16, __ATOMIC_ACQUIRE, __HIP_MEMORY_SCOPE_AGENT) == gen)
        __builtin_amdgcn_s_sleep(2);
    }
    __threadfence();                     // agent-scope acquire: invalidate stale cache
  }
  __syncthreads();
}

// A-frags from LDS (own-wave 16 rows, stride AST), B-frags packed in wbuf slot
__device__ __forceinline__ void gemm_lds(const __bf16* __restrict__ Arow,
                                         const __bf16* __restrict__ wb,
                                         int lane, f32x4 acc[8]) {
  int quad = lane >> 4, m = lane & 15;
  bf16x8 a[4];
#pragma unroll
  for (int ks = 0; ks < 4; ks++)
    a[ks] = *(const bf16x8*)(Arow + m * AST + ks * 32 + quad * 8);
#pragma unroll
  for (int ct = 0; ct < 8; ct++)
#pragma unroll
    for (int ks = 0; ks < 4; ks++) {
      bf16x8 b = *(const bf16x8*)(wb + ((ct * 4 + ks) * 64 + lane) * 8);
      acc[ct] = __builtin_amdgcn_mfma_f32_16x16x32_bf16(a[ks], b, acc[ct], 0, 0, 0);
    }
}

__device__ __forceinline__ void gemm_reg(const bf16x8 a[4],
                                         const __bf16* __restrict__ wb,
                                         int lane, f32x4 acc[8]) {
#pragma unroll
  for (int ct = 0; ct < 8; ct++)
#pragma unroll
    for (int ks = 0; ks < 4; ks++) {
      bf16x8 b = *(const bf16x8*)(wb + ((ct * 4 + ks) * 64 + lane) * 8);
      acc[ct] = __builtin_amdgcn_mfma_f32_16x16x32_bf16(a[ks], b, acc[ct], 0, 0, 0);
    }
}

__global__ __launch_bounds__(256) void giph_all(GiphParams P) {
  __shared__ __bf16 wbuf[2][16384];   // 64 KB: [0]=GEMM1 weights, [1]=GEMM2 weights
  __shared__ __bf16 Ast[64 * AST];    // 17 KB staging (per-wave 16-row regions)
  int tid = threadIdx.x;
  int bid = blockIdx.x;
  int gtid = bid * 256 + tid;
  int lane = tid & 63, wv = tid >> 6, quad = lane >> 4, c16 = lane & 15;

  // ================= P0: pack weights (bf16 B-frag order) + zero deg ==========
  {
    const float* ws[6] = {P.nt_w1, P.nt_w2, P.f_upd_w, P.f_pre_w, P.b_upd_w, P.b_pre_w};
    for (int i = gtid; i < 6 * 16384; i += 65536) {
      int mat = i >> 14, r = i & 16383;
      int j = r & 7, f = r >> 3;
      int ln = f & 63, ctks = f >> 6;
      int ks = ctks & 3, ct = ctks >> 2;
      int k = ks * 32 + ((ln >> 4) << 3) + j;
      int n = (ct << 4) + (ln & 15);
      P.wpk[i] = (__bf16)ws[mat][k * 128 + n];
    }
    for (int i = gtid; i < NLVL * PP; i += 65536) P.deg[i] = 0;
  }
  grid_barrier(P.bar, tid);

  // ================= P1: CSR count ==========
  for (int e = gtid; e < NLVL * NE; e += 65536)
    atomicAdd(&P.deg[(e >> 16) * PP + P.src[e]], 1);
  grid_barrier(P.bar, tid);

  // ================= P2: CSR scan (blocks 0..14) + preload nt weights ==========
  if (bid < NLVL) {
    int* ssum = (int*)Ast;
    const int* d = P.deg + bid * PP;
    int loc[32];
    int sv = 0;
#pragma unroll
    for (int j = 0; j < 32; j++) { loc[j] = d[tid * 32 + j]; sv += loc[j]; }
    ssum[tid] = sv;
    __syncthreads();
    for (int off = 1; off < 256; off <<= 1) {
      int v = (tid >= off) ? ssum[tid - off] : 0;
      __syncthreads();
      ssum[tid] += v;
      __syncthreads();
    }
    int run = (tid == 0) ? 0 : ssum[tid - 1];
#pragma unroll
    for (int j = 0; j < 32; j++) {
      P.offs[bid * (PP + 1) + tid * 32 + j] = run;
      P.cursor[bid * PP + tid * 32 + j] = run;
      run += loc[j];
    }
    if (tid == 255) P.offs[bid * (PP + 1) + PP] = run;
    __syncthreads();
  }
  {
    const float4* s0 = (const float4*)P.wpk;            // nt_w1 packed
    const float4* s1 = (const float4*)(P.wpk + 16384);  // nt_w2 packed
    float4* d0 = (float4*)wbuf[0];
    float4* d1 = (float4*)wbuf[1];
#pragma unroll
    for (int i = 0; i < 8; i++) {
      d0[tid + i * 256] = s0[tid + i * 256];
      d1[tid + i * 256] = s1[tid + i * 256];
    }
  }
  grid_barrier(P.bar, tid);

  // ================= P3: CSR fill + node transform ==========
  for (int e = bid * 3840 + tid; e < (bid + 1) * 3840; e += 256) {
    int l = e >> 16;
    int q = P.src[e];
    int pos = atomicAdd(&P.cursor[l * PP + q], 1);
    P.edges[l * NE + pos] = (e & (NE - 1)) >> 3;
  }
  for (int it = 0; it < 8; it++) {
    size_t base = ((size_t)(bid * 8 + it)) * 64 + wv * 16;  // this wave's 16 rows
    __bf16* Aw = Ast + wv * 16 * AST;
    const float4* xs = (const float4*)(P.x + base * 128);
#pragma unroll
    for (int j = 0; j < 8; j++) {
      int idx = lane + j * 64;
      float4 v = xs[idx];
      int r = idx >> 5, c = (idx & 31) * 4;
      union { __bf16 b[4]; uint2 u; } pk;
      pk.b[0] = (__bf16)v.x; pk.b[1] = (__bf16)v.y;
      pk.b[2] = (__bf16)v.z; pk.b[3] = (__bf16)v.w;
      *(uint2*)(Aw + r * AST + c) = pk.u;
    }
    f32x4 acc[8];
#pragma unroll
    for (int ct = 0; ct < 8; ct++) acc[ct] = (f32x4){0.f, 0.f, 0.f, 0.f};
    gemm_lds(Aw, wbuf[0], lane, acc);
#pragma unroll
    for (int ct = 0; ct < 8; ct++) {
      int col = ct * 16 + c16;
      float bias = P.nt_b1[col];
#pragma unroll
      for (int rg = 0; rg < 4; rg++)
        Aw[(quad * 4 + rg) * AST + col] = (__bf16)fmaxf(acc[ct][rg] + bias, 0.f);
    }
#pragma unroll
    for (int ct = 0; ct < 8; ct++) acc[ct] = (f32x4){0.f, 0.f, 0.f, 0.f};
    gemm_lds(Aw, wbuf[1], lane, acc);
#pragma unroll
    for (int ct = 0; ct < 8; ct++) {
      int col = ct * 16 + c16;
      float bias = P.nt_b2[col];
#pragma unroll
      for (int rg = 0; rg < 4; rg++)
        P.h[(base + quad * 4 + rg) * 128 + col] = acc[ct][rg] + bias;
    }
  }

  // ---- load this block's direction weights for all 16 levels ----
  bool is_fwd = bid < 128;
  __syncthreads();   // everyone done with wbuf (nt) before overwrite
  {
    const float4* s0 = (const float4*)(P.wpk + (is_fwd ? 2 : 4) * 16384);  // upd
    const float4* s1 = (const float4*)(P.wpk + (is_fwd ? 3 : 5) * 16384);  // pre
    float4* d0 = (float4*)wbuf[0];
    float4* d1 = (float4*)wbuf[1];
#pragma unroll
    for (int i = 0; i < 8; i++) {
      d0[tid + i * 256] = s0[tid + i * 256];
      d1[tid + i * 256] = s1[tid + i * 256];
    }
  }
  grid_barrier(P.bar, tid);

  // ================= P4: 16 message-passing levels ==========
  int tile = (bid & 127) * 64;
  const float* updb = is_fwd ? P.f_upd_b : P.b_upd_b;
  const float* preb = is_fwd ? P.f_pre_b : P.b_pre_b;
  int col_off = is_fwd ? 0 : 128;
  int p_row = tile + wv * 16 + c16;   // this lane's gather row within the level

  for (int s = 0; s < 16; s++) {
    int level = is_fwd ? s : 15 - s;
    const __bf16* m_in = is_fwd ? ((s & 1) ? P.mf0 : P.mf1) : ((s & 1) ? P.mb0 : P.mb1);
    __bf16* m_out      = is_fwd ? ((s & 1) ? P.mf1 : P.mf0) : ((s & 1) ? P.mb1 : P.mb0);

    // ---- fragment-direct gather: fp32 accumulate this lane's A-frag elems ----
    float g[4][8];
#pragma unroll
    for (int ks = 0; ks < 4; ks++)
#pragma unroll
      for (int j = 0; j < 8; j++) g[ks][j] = 0.f;

    if (s > 0) {
      if (is_fwd) {
        const int* sl = P.src + (s - 1) * NE + p_row * 8;
#pragma unroll
        for (int k = 0; k < 8; k++) {
          int si = sl[k];
          const uint4* mp_ = (const uint4*)(m_in + (size_t)si * 128 + quad * 8);
#pragma unroll
          for (int ks = 0; ks < 4; ks++) {
            uint4 raw = mp_[ks * 4];
            g[ks][0] += bf_lo(raw.x); g[ks][1] += bf_hi(raw.x);
            g[ks][2] += bf_lo(raw.y); g[ks][3] += bf_hi(raw.y);
            g[ks][4] += bf_lo(raw.z); g[ks][5] += bf_hi(raw.z);
            g[ks][6] += bf_lo(raw.w); g[ks][7] += bf_hi(raw.w);
          }
        }
#pragma unroll
        for (int ks = 0; ks < 4; ks++)
#pragma unroll
          for (int j = 0; j < 8; j++) g[ks][j] *= 0.125f;
      } else {
        const int* off_l = P.offs + level * (PP + 1);
        int lo = off_l[p_row], hi = off_l[p_row + 1];
        const int* ep = P.edges + level * NE;
        for (int idx = lo; idx < hi; idx++) {
          int pp = ep[idx];
          const uint4* mp_ = (const uint4*)(m_in + (size_t)pp * 128 + quad * 8);
#pragma unroll
          for (int ks = 0; ks < 4; ks++) {
            uint4 raw = mp_[ks * 4];
            g[ks][0] += bf_lo(raw.x); g[ks][1] += bf_hi(raw.x);
            g[ks][2] += bf_lo(raw.y); g[ks][3] += bf_hi(raw.y);
            g[ks][4] += bf_lo(raw.z); g[ks][5] += bf_hi(raw.z);
            g[ks][6] += bf_lo(raw.w); g[ks][7] += bf_hi(raw.w);
          }
        }
        float inv = (hi > lo) ? 1.f / (float)(hi - lo) : 0.f;
#pragma unroll
        for (int ks = 0; ks < 4; ks++)
#pragma unroll
          for (int j = 0; j < 8; j++) g[ks][j] *= inv;
      }
    }
    bf16x8 a[4];
#pragma unroll
    for (int ks = 0; ks < 4; ks++)
#pragma unroll
      for (int j = 0; j < 8; j++) a[ks][j] = (__bf16)g[ks][j];

    // ---- GEMM1: u = relu(z@upd_w + upd_b) + h ; write out half; u -> LDS ----
    f32x4 acc[8];
#pragma unroll
    for (int ct = 0; ct < 8; ct++) acc[ct] = (f32x4){0.f, 0.f, 0.f, 0.f};
    gemm_reg(a, wbuf[0], lane, acc);

    size_t nbase = (size_t)level * PP + tile + wv * 16;
#pragma unroll
    for (int ct = 0; ct < 8; ct++) {
      int col = ct * 16 + c16;
      float bias = updb[col];
#pragma unroll
      for (int rg = 0; rg < 4; rg++) {
        size_t n = nbase + quad * 4 + rg;
        float v = fmaxf(acc[ct][rg] + bias, 0.f) + P.h[n * 128 + col];
        P.out[n * 256 + col_off + col] = v;
        Ast[(wv * 16 + quad * 4 + rg) * AST + col] = (__bf16)v;
      }
    }

    // ---- GEMM2: m_out = relu(u @ pre_w + pre_b) ----
    if (s < 15) {
#pragma unroll
      for (int ct = 0; ct < 8; ct++) acc[ct] = (f32x4){0.f, 0.f, 0.f, 0.f};
      gemm_lds(Ast + wv * 16 * AST, wbuf[1], lane, acc);
#pragma unroll
      for (int ct = 0; ct < 8; ct++) {
        int col = ct * 16 + c16;
        float bias = preb[col];
#pragma unroll
        for (int rg = 0; rg < 4; rg++)
          m_out[((size_t)(tile + wv * 16 + quad * 4 + rg)) * 128 + col] =
              (__bf16)fmaxf(acc[ct][rg] + bias, 0.f);
      }
      grid_barrier(P.bar, tid);
    }
  }
}

extern "C" void kernel_launch(void* const* d_in, const int* in_sizes, int n_in,
                              void* d_out, int out_size, void* d_ws, size_t ws_size,
                              hipStream_t stream) {
  GiphParams P;
  P.x       = (const float*)d_in[0];
  P.src     = (const int*)d_in[1];
  P.nt_w1   = (const float*)d_in[2];
  P.nt_b1   = (const float*)d_in[3];
  P.nt_w2   = (const float*)d_in[4];
  P.nt_b2   = (const float*)d_in[5];
  P.f_pre_w = (const float*)d_in[6];
  P.f_pre_b = (const float*)d_in[7];
  P.f_upd_w = (const float*)d_in[8];
  P.f_upd_b = (const float*)d_in[9];
  P.b_pre_w = (const float*)d_in[10];
  P.b_pre_b = (const float*)d_in[11];
  P.b_upd_w = (const float*)d_in[12];
  P.b_upd_b = (const float*)d_in[13];
  P.out = (float*)d_out;

  char* wsb = (char*)d_ws;
  P.bar = (int*)wsb;                                     // 128 B barrier state
  P.h   = (float*)(wsb + 128);                           // 64 MB
  P.mf0 = (__bf16*)(wsb + 128 + (size_t)NN * 128 * 4);
  P.mf1 = P.mf0 + (size_t)PP * 128;
  P.mb0 = P.mf1 + (size_t)PP * 128;
  P.mb1 = P.mb0 + (size_t)PP * 128;
  P.wpk = P.mb1 + (size_t)PP * 128;                      // 6 x 32 KB packed
  P.deg    = (int*)(P.wpk + 6 * 16384);
  P.offs   = P.deg + NLVL * PP;
  P.cursor = P.offs + NLVL * (PP + 1);
  P.edges  = P.cursor + NLVL * PP;

  hipMemsetAsync(P.bar, 0, 128, stream);
  giph_all<<<NBLK, 256, 0, stream>>>(P);
}